// Round 7
// baseline (92.968 us; speedup 1.0000x reference)
//
#include <hip/hip_runtime.h>
#include <hip/hip_bf16.h>

#define JT 256  // j-lanes per block; NI = 1 (one i per block)

// Per-box derived data:
//  R[9] = rotation rows (row-major)
//  c[3] = transformed center: (mn + 0.5*dims) @ R + t
//  e[9] = rows e_d = dims_d * R[d,:]
__device__ __forceinline__ void load_box(const float* __restrict__ bb,
                                         const float* __restrict__ rot,
                                         const float* __restrict__ tr,
                                         int b, float* R, float* c, float* e) {
    const float* s = bb + b * 6;
    const float* r = rot + b * 9;
    const float* t = tr + b * 3;
    float d0 = s[3], d1 = s[4], d2 = s[5];
    float a0 = s[0] + 0.5f * d0, a1 = s[1] + 0.5f * d1, a2 = s[2] + 0.5f * d2;
#pragma unroll
    for (int k = 0; k < 9; k++) R[k] = r[k];
#pragma unroll
    for (int k = 0; k < 3; k++) {
        c[k]     = a0 * R[k] + a1 * R[3 + k] + a2 * R[6 + k] + t[k];
        e[k]     = d0 * R[k];
        e[3 + k] = d1 * R[3 + k];
        e[6 + k] = d2 * R[6 + k];
    }
}

// Interval overlap of the two boxes' projections on one axis.
// s = center proj, h = half extent; ov = min(hi1,hi2) - max(lo1,lo2)
// (== reference's sum_len - total_len in all cases, incl. containment)
__device__ __forceinline__ float axis_overlap(float ax, float ay, float az,
                                              const float* ci, const float* ei,
                                              const float* cj, const float* ej) {
    float s1 = ci[0] * ax + ci[1] * ay + ci[2] * az;
    float u0 = ei[0] * ax + ei[1] * ay + ei[2] * az;
    float u1 = ei[3] * ax + ei[4] * ay + ei[5] * az;
    float u2 = ei[6] * ax + ei[7] * ay + ei[8] * az;
    float h1 = 0.5f * (fabsf(u0) + fabsf(u1) + fabsf(u2));

    float s2 = cj[0] * ax + cj[1] * ay + cj[2] * az;
    float v0 = ej[0] * ax + ej[1] * ay + ej[2] * az;
    float v1 = ej[3] * ax + ej[4] * ay + ej[5] * az;
    float v2 = ej[6] * ax + ej[7] * ay + ej[8] * az;
    float h2 = 0.5f * (fabsf(v0) + fabsf(v1) + fabsf(v2));

    return fminf(s1 + h1, s2 + h2) - fmaxf(s1 - h1, s2 - h2);
}

// Triangle-only 1D grid, NI=1: block = (jc, i). i is block-uniform -> scalar loads.
__global__ __launch_bounds__(JT) void pv_pairs(const float* __restrict__ bb,
                                               const float* __restrict__ rot,
                                               const float* __restrict__ tr,
                                               float* __restrict__ out, int B) {
    // blocks per jc chunk: (jc+1)*JT (capped at B); decode bid -> (jc, i)
    int bid = blockIdx.x;
    int jc = 0, base = 0, i = 0;
    for (;; jc++) {  // gx = B/JT = 4; few SALU ops
        int icmax = min((jc + 1) * JT, B);
        if (bid < base + icmax) { i = bid - base; break; }
        base += icmax;
    }
    const int j = jc * JT + threadIdx.x;

    float pen = 0.0f;
    if (j < B && j > i) {
        // i-side box: block-uniform -> s_load + scalar-friendly
        float Ri[9], ci[3], ei[9];
        load_box(bb, rot, tr, i, Ri, ci, ei);
        // j-side box: per-lane
        float Rj[9], cj[3], ej[9];
        load_box(bb, rot, tr, j, Rj, cj, ej);

        bool pass = true;
        float minov = __builtin_inff();

        // 3 face axes of box i (reference dedups its duplicated first-box pass)
#pragma unroll
        for (int a = 0; a < 3; a++) {
            float ov = axis_overlap(Ri[a * 3], Ri[a * 3 + 1], Ri[a * 3 + 2],
                                    ci, ei, cj, ej);
            pass = pass && (ov > 0.0f);
            minov = fminf(minov, ov);
        }
        // 6 cross axes: (A,B) in {(0,0),(0,1),(0,2),(1,1),(1,2),(2,2)}
        const int CA[6] = {0, 0, 0, 1, 1, 2};
        const int CB[6] = {0, 1, 2, 1, 2, 2};
#pragma unroll
        for (int cc = 0; cc < 6; cc++) {
            const int ra = CA[cc], rb = CB[cc];
            float ux = Ri[ra * 3], uy = Ri[ra * 3 + 1], uz = Ri[ra * 3 + 2];
            float vx = Rj[rb * 3], vy = Rj[rb * 3 + 1], vz = Rj[rb * 3 + 2];
            float ax = uy * vz - uz * vy;
            float ay = uz * vx - ux * vz;
            float az = ux * vy - uy * vx;
            if ((ax != 0.0f) || (ay != 0.0f) || (az != 0.0f)) {
                float ov = axis_overlap(ax, ay, az, ci, ei, cj, ej);
                pass = pass && (ov > 0.0f);
                minov = fminf(minov, ov);
            }
        }
        pen = pass ? minov : 0.0f;
    }

    // wave shfl reduce -> LDS combine -> ONE atomicAdd per block
#pragma unroll
    for (int off = 32; off > 0; off >>= 1) pen += __shfl_down(pen, off);
    __shared__ float wsum[JT / 64];
    const int wid = threadIdx.x >> 6;
    if ((threadIdx.x & 63) == 0) wsum[wid] = pen;
    __syncthreads();
    if (threadIdx.x == 0) {
        float s = 0.0f;
#pragma unroll
        for (int w = 0; w < JT / 64; w++) s += wsum[w];
        atomicAdd(out, s);
    }
}

extern "C" void kernel_launch(void* const* d_in, const int* in_sizes, int n_in,
                              void* d_out, int out_size, void* d_ws, size_t ws_size,
                              hipStream_t stream) {
    const float* bb  = (const float*)d_in[0];   // [B,6]
    const float* rot = (const float*)d_in[1];   // [B,3,3]
    const float* tr  = (const float*)d_in[2];   // [B,1,3]
    float* out = (float*)d_out;                  // scalar
    const int B = in_sizes[0] / 6;

    // zero the scalar accumulator (d_out is poisoned 0xAA before every call)
    hipMemsetAsync(out, 0, sizeof(float), stream);

    // triangle block count: sum over jc of min((jc+1)*JT, B)
    const int gx = (B + JT - 1) / JT;
    int total = 0;
    for (int jc = 0; jc < gx; jc++) {
        int icmax = (jc + 1) * JT;
        total += (icmax < B) ? icmax : B;
    }

    pv_pairs<<<dim3(total), dim3(JT), 0, stream>>>(bb, rot, tr, out, B);
}

// Round 8
// 68.842 us; speedup vs baseline: 1.3505x; 1.3505x over previous
//
#include <hip/hip_runtime.h>
#include <hip/hip_bf16.h>

#define NI 2    // i-values (pairs) per thread
#define JT 256  // j-lanes per block

// Per-box derived data:
//  R[9] = rotation rows (row-major)
//  c[3] = box center transformed: (mn + 0.5*dims) @ R + t
//  e[9] = rows e_d = dims_d * R[d,:]
__device__ __forceinline__ void load_box(const float* __restrict__ bb,
                                         const float* __restrict__ rot,
                                         const float* __restrict__ tr,
                                         int b, float* R, float* c, float* e) {
    const float* s = bb + b * 6;
    const float* r = rot + b * 9;
    const float* t = tr + b * 3;
    float d0 = s[3], d1 = s[4], d2 = s[5];
    float a0 = s[0] + 0.5f * d0, a1 = s[1] + 0.5f * d1, a2 = s[2] + 0.5f * d2;
#pragma unroll
    for (int k = 0; k < 9; k++) R[k] = r[k];
#pragma unroll
    for (int k = 0; k < 3; k++) {
        c[k]     = a0 * R[k] + a1 * R[3 + k] + a2 * R[6 + k] + t[k];
        e[k]     = d0 * R[k];
        e[3 + k] = d1 * R[3 + k];
        e[6 + k] = d2 * R[6 + k];
    }
}

// Interval overlap of the two boxes' projections on one axis.
// s = center proj, h = half extent; ov = min(hi1,hi2) - max(lo1,lo2)
// (identical to the reference's sum_len - total_len for ALL cases, incl. containment)
__device__ __forceinline__ float axis_overlap(float ax, float ay, float az,
                                              const float* ci, const float* ei,
                                              const float* cj, const float* ej) {
    float s1 = ci[0] * ax + ci[1] * ay + ci[2] * az;
    float u0 = ei[0] * ax + ei[1] * ay + ei[2] * az;
    float u1 = ei[3] * ax + ei[4] * ay + ei[5] * az;
    float u2 = ei[6] * ax + ei[7] * ay + ei[8] * az;
    float h1 = 0.5f * (fabsf(u0) + fabsf(u1) + fabsf(u2));

    float s2 = cj[0] * ax + cj[1] * ay + cj[2] * az;
    float v0 = ej[0] * ax + ej[1] * ay + ej[2] * az;
    float v1 = ej[3] * ax + ej[4] * ay + ej[5] * az;
    float v2 = ej[6] * ax + ej[7] * ay + ej[8] * az;
    float h2 = 0.5f * (fabsf(v0) + fabsf(v1) + fabsf(v2));

    return fminf(s1 + h1, s2 + h2) - fmaxf(s1 - h1, s2 - h2);
}

// Triangle-only grid: 1D blocks decode to (jc, ic); every block has work.
__global__ __launch_bounds__(JT) void pv_pairs(const float* __restrict__ bb,
                                               const float* __restrict__ rot,
                                               const float* __restrict__ tr,
                                               float* __restrict__ partial, int B) {
    const int icAll = (B + NI - 1) / NI;
    int bid = blockIdx.x;
    int jc = 0, base = 0, ic = 0;
    for (;; jc++) {  // gx is tiny (B/JT = 4); a few SALU ops
        int icmax = min(((jc + 1) * JT + NI - 1) / NI, icAll);
        if (bid < base + icmax) { ic = bid - base; break; }
        base += icmax;
    }
    const int jbase = jc * JT;
    const int ibase = ic * NI;
    const int j = jbase + threadIdx.x;

    float pen = 0.0f;
    if (j < B) {
        // j-side box: computed once, register-resident for all NI pairs
        float Rj[9], cj[3], ej[9];
        load_box(bb, rot, tr, j, Rj, cj, ej);

#pragma unroll
        for (int ii = 0; ii < NI; ii++) {
            const int i = ibase + ii;
            if (i >= B) break;
            if (i >= j) continue;  // exec-mask; i wave-uniform -> scalar loads
            float Ri[9], ci[3], ei[9];
            load_box(bb, rot, tr, i, Ri, ci, ei);

            bool pass = true;
            float minov = __builtin_inff();

            // 3 face axes of box i (reference dedups its duplicated first-box pass)
#pragma unroll
            for (int a = 0; a < 3; a++) {
                float ov = axis_overlap(Ri[a * 3], Ri[a * 3 + 1], Ri[a * 3 + 2],
                                        ci, ei, cj, ej);
                pass = pass && (ov > 0.0f);
                minov = fminf(minov, ov);
            }
            // 6 cross axes: (A,B) in {(0,0),(0,1),(0,2),(1,1),(1,2),(2,2)}
            const int CA[6] = {0, 0, 0, 1, 1, 2};
            const int CB[6] = {0, 1, 2, 1, 2, 2};
#pragma unroll
            for (int cc = 0; cc < 6; cc++) {
                const int ra = CA[cc], rb = CB[cc];
                float ux = Ri[ra * 3], uy = Ri[ra * 3 + 1], uz = Ri[ra * 3 + 2];
                float vx = Rj[rb * 3], vy = Rj[rb * 3 + 1], vz = Rj[rb * 3 + 2];
                float ax = uy * vz - uz * vy;
                float ay = uz * vx - ux * vz;
                float az = ux * vy - uy * vx;
                if ((ax != 0.0f) || (ay != 0.0f) || (az != 0.0f)) {
                    float ov = axis_overlap(ax, ay, az, ci, ei, cj, ej);
                    pass = pass && (ov > 0.0f);
                    minov = fminf(minov, ov);
                }
            }
            pen += pass ? minov : 0.0f;
        }
    }

    // wave shfl reduce, tiny LDS combine, one plain store per block (no atomics)
#pragma unroll
    for (int off = 32; off > 0; off >>= 1) pen += __shfl_down(pen, off);
    __shared__ float wsum[JT / 64];
    const int wid = threadIdx.x >> 6;
    if ((threadIdx.x & 63) == 0) wsum[wid] = pen;
    __syncthreads();
    if (threadIdx.x == 0) {
        float s = 0.0f;
#pragma unroll
        for (int w = 0; w < JT / 64; w++) s += wsum[w];
        partial[blockIdx.x] = s;
    }
}

__global__ __launch_bounds__(256) void pv_reduce(const float* __restrict__ partial,
                                                 float* __restrict__ out, int n) {
    float s = 0.0f;
    for (int k = threadIdx.x; k < n; k += 256) s += partial[k];
#pragma unroll
    for (int off = 32; off > 0; off >>= 1) s += __shfl_down(s, off);
    __shared__ float wsum[4];
    const int wid = threadIdx.x >> 6;
    if ((threadIdx.x & 63) == 0) wsum[wid] = s;
    __syncthreads();
    if (threadIdx.x == 0) out[0] = wsum[0] + wsum[1] + wsum[2] + wsum[3];
}

extern "C" void kernel_launch(void* const* d_in, const int* in_sizes, int n_in,
                              void* d_out, int out_size, void* d_ws, size_t ws_size,
                              hipStream_t stream) {
    const float* bb  = (const float*)d_in[0];   // [B,6]
    const float* rot = (const float*)d_in[1];   // [B,3,3]
    const float* tr  = (const float*)d_in[2];   // [B,1,3]
    float* out = (float*)d_out;                  // scalar
    const int B = in_sizes[0] / 6;

    float* partial = (float*)d_ws;

    // count active (triangle) tiles
    const int gx = (B + JT - 1) / JT;
    const int icAll = (B + NI - 1) / NI;
    int total = 0;
    for (int jc = 0; jc < gx; jc++) {
        int icmax = ((jc + 1) * JT + NI - 1) / NI;
        total += (icmax < icAll) ? icmax : icAll;
    }

    pv_pairs<<<dim3(total), dim3(JT), 0, stream>>>(bb, rot, tr, partial, B);
    pv_reduce<<<1, 256, 0, stream>>>(partial, out, total);
}